// Round 1
// baseline (80.187 us; speedup 1.0000x reference)
//
#include <hip/hip_runtime.h>
#include <hip/hip_bf16.h>

#define N_VERT 163842
#define K_TOT  448          // 7 * 64
#define BM     64           // vertices per block tile
#define KS_N   14           // 448 / 32
#define LDS_K  456          // padded K row (bf16 elems): 912 B stride, 912 % 128 = 16 -> bank spread

typedef float  f32x4  __attribute__((ext_vector_type(4)));
typedef short  s16x8  __attribute__((ext_vector_type(8)));

__device__ __forceinline__ unsigned short f2bf(float f) {
  union { float f; unsigned int u; } c; c.f = f;
  unsigned int u = c.u;
  u += 0x7FFFu + ((u >> 16) & 1u);   // RNE truncate to bf16
  return (unsigned short)(u >> 16);
}

// hex_in dtype sniffer: int64 data has all-zero odd u32 words (values < 2^18).
__global__ void detect64(const unsigned int* __restrict__ hexw, int* __restrict__ flag) {
  __shared__ int any;
  if (threadIdx.x == 0) any = 0;
  __syncthreads();
  if (hexw[2 * threadIdx.x + 1] != 0u) any = 1;   // first 256 candidate int64s
  __syncthreads();
  if (threadIdx.x == 0) *flag = (any == 0) ? 1 : 0;  // 1 => int64, 0 => int32
}

__global__ __launch_bounds__(256) void hexconv(
    const float* __restrict__ x,
    const unsigned int* __restrict__ hexw,
    const float* __restrict__ W,      // [448][64] row-major f32
    const float* __restrict__ bias,   // [64]
    float* __restrict__ out,          // [N_VERT][64] f32
    const int* __restrict__ flag)
{
  __shared__ unsigned short A[BM * LDS_K];   // 58368 B

  const int tid = threadIdx.x;
  const int wv  = tid >> 6;         // wave 0..3 -> output cols [16*wv, 16*wv+16)
  const int ln  = tid & 63;
  const int lo  = ln & 15;
  const int hi  = ln >> 4;
  const int is64 = flag ? *flag : 1;

  // ---- B fragments (W) in registers: lane holds W[k][col], k = ks*32 + hi*8 + e
  const int col = wv * 16 + lo;
  s16x8 bfrag[KS_N];
#pragma unroll
  for (int ks = 0; ks < KS_N; ++ks) {
    const float* wp = W + (ks * 32 + hi * 8) * 64 + col;
    s16x8 bv = {0,0,0,0,0,0,0,0};
#pragma unroll
    for (int e = 0; e < 8; ++e)
      bv[e] = (short)f2bf(wp[e * 64]);
    bfrag[ks] = bv;
  }

  const int tile  = blockIdx.x;
  const int vbase = tile * BM;

  // ---- gather A tile into LDS as bf16: A[v][j*64 + f] = x[hex[v*7+j]][f]
#pragma unroll
  for (int it = 0; it < 7; ++it) {
    const int task = it * 256 + tid;   // 448 gather-rows * 4 segments = 1792 tasks
    const int g = task >> 2;           // gather-row 0..447
    const int s = task & 3;            // 16-float segment within the 64-feat row
    const int v = g / 7;
    const int j = g - v * 7;
    const int gv = vbase + v;
    s16x8 h0 = {0,0,0,0,0,0,0,0};
    s16x8 h1 = {0,0,0,0,0,0,0,0};
    if (gv < N_VERT) {
      const long long r = (long long)gv * 7 + j;
      const int idx = (int)hexw[r << is64];     // int64: low word at 2r; int32: word at r
      const f32x4* src = (const f32x4*)(x + (size_t)idx * 64 + s * 16);
      const f32x4 a0 = src[0], a1 = src[1], a2 = src[2], a3 = src[3];
      h0[0] = (short)f2bf(a0[0]); h0[1] = (short)f2bf(a0[1]);
      h0[2] = (short)f2bf(a0[2]); h0[3] = (short)f2bf(a0[3]);
      h0[4] = (short)f2bf(a1[0]); h0[5] = (short)f2bf(a1[1]);
      h0[6] = (short)f2bf(a1[2]); h0[7] = (short)f2bf(a1[3]);
      h1[0] = (short)f2bf(a2[0]); h1[1] = (short)f2bf(a2[1]);
      h1[2] = (short)f2bf(a2[2]); h1[3] = (short)f2bf(a2[3]);
      h1[4] = (short)f2bf(a3[0]); h1[5] = (short)f2bf(a3[1]);
      h1[6] = (short)f2bf(a3[2]); h1[7] = (short)f2bf(a3[3]);
    }
    unsigned short* dst = &A[v * LDS_K + j * 64 + s * 16];
    *(s16x8*)(dst)     = h0;
    *(s16x8*)(dst + 8) = h1;
  }
  __syncthreads();

  // ---- MFMA: wave wv computes rows [0,64) x cols [16wv, 16wv+16)
  f32x4 acc[4];
#pragma unroll
  for (int mt = 0; mt < 4; ++mt) acc[mt] = (f32x4){0.f, 0.f, 0.f, 0.f};

#pragma unroll
  for (int ks = 0; ks < KS_N; ++ks) {
#pragma unroll
    for (int mt = 0; mt < 4; ++mt) {
      const s16x8 af = *(const s16x8*)&A[(mt * 16 + lo) * LDS_K + ks * 32 + hi * 8];
      acc[mt] = __builtin_amdgcn_mfma_f32_16x16x32_bf16(af, bfrag[ks], acc[mt], 0, 0, 0);
    }
  }

  // ---- epilogue: C row = (hi*4 + i), col = lo (m89-verified C/D layout), add bias
  const float bval = bias[col];
#pragma unroll
  for (int mt = 0; mt < 4; ++mt) {
#pragma unroll
    for (int i = 0; i < 4; ++i) {
      const int row = vbase + mt * 16 + hi * 4 + i;
      if (row < N_VERT) out[(size_t)row * 64 + col] = acc[mt][i] + bval;
    }
  }
}

extern "C" void kernel_launch(void* const* d_in, const int* in_sizes, int n_in,
                              void* d_out, int out_size, void* d_ws, size_t ws_size,
                              hipStream_t stream) {
  const float*        x    = (const float*)d_in[0];
  const unsigned int* hexw = (const unsigned int*)d_in[1];
  const float*        W    = (const float*)d_in[2];
  const float*        b    = (const float*)d_in[3];
  float*              out  = (float*)d_out;

  int* flag = (ws_size >= sizeof(int)) ? (int*)d_ws : nullptr;
  if (flag) detect64<<<1, 256, 0, stream>>>(hexw, flag);

  const int grid = (N_VERT + BM - 1) / BM;   // 2561
  hexconv<<<grid, 256, 0, stream>>>(x, hexw, W, b, out, flag);
}

// Round 2
// 55.913 us; speedup vs baseline: 1.4341x; 1.4341x over previous
//
#include <hip/hip_runtime.h>
#include <hip/hip_bf16.h>

#define N_VERT 163842
#define N8_X   1310736      // N_VERT*64/8

typedef float  f32x4  __attribute__((ext_vector_type(4)));
typedef short  s16x8  __attribute__((ext_vector_type(8)));

__device__ __forceinline__ unsigned short f2bf(float f) {
  union { float f; unsigned int u; } c; c.f = f;
  unsigned int u = c.u;
  u += 0x7FFFu + ((u >> 16) & 1u);   // RNE truncate to bf16
  return (unsigned short)(u >> 16);
}

__device__ __forceinline__ s16x8 cvt8(const f32x4 a, const f32x4 b) {
  s16x8 h;
  h[0] = (short)f2bf(a[0]); h[1] = (short)f2bf(a[1]);
  h[2] = (short)f2bf(a[2]); h[3] = (short)f2bf(a[3]);
  h[4] = (short)f2bf(b[0]); h[5] = (short)f2bf(b[1]);
  h[6] = (short)f2bf(b[2]); h[7] = (short)f2bf(b[3]);
  return h;
}

// hex_in dtype sniffer: int64 data has all-zero odd u32 words (values < 2^18).
__global__ void detect64(const unsigned int* __restrict__ hexw, int* __restrict__ flag) {
  __shared__ int any;
  if (threadIdx.x == 0) any = 0;
  __syncthreads();
  if (hexw[2 * threadIdx.x + 1] != 0u) any = 1;
  __syncthreads();
  if (threadIdx.x == 0) *flag = (any == 0) ? 1 : 0;  // 1 => int64, 0 => int32
}

// x (f32 [N][64]) -> xbf (bf16 [N][64])
__global__ __launch_bounds__(256) void cvt_x_kernel(const float* __restrict__ x,
                                                    unsigned short* __restrict__ xbf) {
  int i = blockIdx.x * 256 + threadIdx.x;
  const int stride = gridDim.x * 256;
  for (; i < N8_X; i += stride) {
    const f32x4* s = (const f32x4*)(x + (size_t)i * 8);
    *(s16x8*)(xbf + (size_t)i * 8) = cvt8(s[0], s[1]);
  }
}

// W (f32 [448][64]) -> Wf fragment-ordered bf16: Wf[((hi*64+col)*14+ks)*8+e] = W[ks*32+hi*8+e][col]
__global__ __launch_bounds__(256) void cvt_w_kernel(const float* __restrict__ W,
                                                    unsigned short* __restrict__ Wf) {
  const int t = blockIdx.x * 256 + threadIdx.x;
  if (t >= 448 * 64) return;
  const int e  = t & 7;
  const int ks = (t >> 3) % 14;
  const int c  = t / (14 * 8);          // c = hi*64 + col
  const int hi = c >> 6, colc = c & 63;
  const int k  = ks * 32 + hi * 8 + e;
  Wf[t] = f2bf(W[k * 64 + colc]);
}

// Main kernel. BF=1: gather from bf16 xbf (128 B rows), W from Wf.
//              BF=0: gather from f32 x (256 B rows), W from f32 (fallback, no ws needed).
template <int BF>
__global__ __launch_bounds__(256, 4) void hexconv2(
    const void* __restrict__ xsrc,
    const unsigned int* __restrict__ hexw,
    const void* __restrict__ wsrc,
    const float* __restrict__ bias,
    float* __restrict__ out,
    const int* __restrict__ flag)
{
  __shared__ unsigned short Abuf[2][64 * 64];   // 2 x 8 KiB bf16 j-tiles
  __shared__ unsigned int idxb[448];            // gathered-row byte offsets

  const int tid = threadIdx.x;
  const int wv  = tid >> 6;          // wave -> output cols [16wv,16wv+16)
  const int ln  = tid & 63;
  const int lo  = ln & 15;
  const int hi  = ln >> 4;
  const int vbase = blockIdx.x * 64;
  const int is64  = flag ? *flag : 1;

  // ---- B fragments (W) in registers
  const int col = (wv << 4) + lo;
  s16x8 bfrag[14];
  if (BF) {
    const s16x8* wf = (const s16x8*)wsrc + ((hi << 6) + col) * 14;
#pragma unroll
    for (int ks = 0; ks < 14; ++ks) bfrag[ks] = wf[ks];
  } else {
    const float* W = (const float*)wsrc;
#pragma unroll
    for (int ks = 0; ks < 14; ++ks) {
      const float* wp = W + (ks * 32 + hi * 8) * 64 + col;
      s16x8 bv;
#pragma unroll
      for (int e = 0; e < 8; ++e) bv[e] = (short)f2bf(wp[e * 64]);
      bfrag[ks] = bv;
    }
  }

  // ---- 448 gather indices -> LDS as byte offsets (guarded for tail block)
  for (int g = tid; g < 448; g += 256) {
    unsigned int ib = 0;
    const int v = g / 7;
    if (vbase + v < N_VERT) {
      const long long r = (long long)vbase * 7 + g;
      const unsigned int idx = hexw[r << is64];
      ib = idx << (BF ? 7 : 8);
    }
    idxb[g] = ib;
  }
  __syncthreads();

  // ---- staging geometry: thread owns row srow, quarter q (16 feats = 32 B bf16 / 64 B f32)
  const int srow = tid >> 2, q = tid & 3;
  const unsigned int swz = (unsigned int)((srow & 7) << 4);
  char* myrow[2] = { (char*)&Abuf[0][0] + srow * 128,
                     (char*)&Abuf[1][0] + srow * 128 };
  const unsigned int wb0 = ((unsigned int)(q * 32))      ^ swz;
  const unsigned int wb1 = ((unsigned int)(q * 32 + 16)) ^ swz;
  const char* xbase = (const char*)xsrc;

  // prologue: stage j=0 into buf0
  {
    const char* p = xbase + idxb[srow * 7] + (BF ? q * 32 : q * 64);
    s16x8 g0, g1;
    if (BF) {
      g0 = *(const s16x8*)p;
      g1 = *(const s16x8*)(p + 16);
    } else {
      const f32x4 r0 = *(const f32x4*)p,        r1 = *(const f32x4*)(p + 16);
      const f32x4 r2 = *(const f32x4*)(p + 32), r3 = *(const f32x4*)(p + 48);
      g0 = cvt8(r0, r1); g1 = cvt8(r2, r3);
    }
    *(s16x8*)(myrow[0] + wb0) = g0;
    *(s16x8*)(myrow[0] + wb1) = g1;
  }
  __syncthreads();

  f32x4 acc[4];
#pragma unroll
  for (int mt = 0; mt < 4; ++mt) acc[mt] = (f32x4){0.f, 0.f, 0.f, 0.f};

  const unsigned int rswz = (unsigned int)((lo & 7) << 4);   // read-side swizzle (r&7 == lo&7)

#pragma unroll
  for (int j = 0; j < 7; ++j) {
    const char* curbuf = (j & 1) ? (const char*)&Abuf[1][0] : (const char*)&Abuf[0][0];
    char* nxtrow = myrow[(j & 1) ^ 1];

    // T14 split: issue next-j gather loads BEFORE the MFMA phase
    s16x8 g0, g1;
    f32x4 r0, r1, r2, r3;
    if (j < 6) {
      const char* p = xbase + idxb[srow * 7 + j + 1] + (BF ? q * 32 : q * 64);
      if (BF) {
        g0 = *(const s16x8*)p;
        g1 = *(const s16x8*)(p + 16);
      } else {
        r0 = *(const f32x4*)p;        r1 = *(const f32x4*)(p + 16);
        r2 = *(const f32x4*)(p + 32); r3 = *(const f32x4*)(p + 48);
      }
    }

    // MFMA on current buffer: K=64 (2 K-steps) x 4 M-tiles
#pragma unroll
    for (int kss = 0; kss < 2; ++kss) {
#pragma unroll
      for (int mt = 0; mt < 4; ++mt) {
        const int r = mt * 16 + lo;
        const s16x8 af = *(const s16x8*)(curbuf + r * 128 +
                           (((unsigned int)(kss * 64 + hi * 16)) ^ rswz));
        acc[mt] = __builtin_amdgcn_mfma_f32_16x16x32_bf16(af, bfrag[2 * j + kss], acc[mt], 0, 0, 0);
      }
    }

    // write-late: convert (f32 path) and store next tile
    if (j < 6) {
      if (!BF) { g0 = cvt8(r0, r1); g1 = cvt8(r2, r3); }
      *(s16x8*)(nxtrow + wb0) = g0;
      *(s16x8*)(nxtrow + wb1) = g1;
    }
    __syncthreads();
  }

  // ---- epilogue
  const float bval = bias[col];
#pragma unroll
  for (int mt = 0; mt < 4; ++mt) {
#pragma unroll
    for (int i = 0; i < 4; ++i) {
      const int row = vbase + mt * 16 + hi * 4 + i;
      if (row < N_VERT) out[(size_t)row * 64 + col] = acc[mt][i] + bval;
    }
  }
}

extern "C" void kernel_launch(void* const* d_in, const int* in_sizes, int n_in,
                              void* d_out, int out_size, void* d_ws, size_t ws_size,
                              hipStream_t stream) {
  const float*        x    = (const float*)d_in[0];
  const unsigned int* hexw = (const unsigned int*)d_in[1];
  const float*        W    = (const float*)d_in[2];
  const float*        b    = (const float*)d_in[3];
  float*              out  = (float*)d_out;

  const size_t WS_NEED = 65536 + (size_t)N_VERT * 64 * 2;   // headers + xbf
  int* flag = (ws_size >= 4) ? (int*)d_ws : nullptr;
  if (flag) detect64<<<1, 256, 0, stream>>>(hexw, flag);

  const int grid = (N_VERT + 63) / 64;   // 2561

  if (flag && ws_size >= WS_NEED) {
    unsigned short* Wf  = (unsigned short*)((char*)d_ws + 4096);
    unsigned short* xbf = (unsigned short*)((char*)d_ws + 65536);
    cvt_w_kernel<<<(448 * 64 + 255) / 256, 256, 0, stream>>>(W, Wf);
    cvt_x_kernel<<<2048, 256, 0, stream>>>(x, xbf);
    hexconv2<1><<<grid, 256, 0, stream>>>(xbf, hexw, Wf, b, out, flag);
  } else {
    hexconv2<0><<<grid, 256, 0, stream>>>(x, hexw, W, b, out, flag);
  }
}

// Round 3
// 45.578 us; speedup vs baseline: 1.7593x; 1.2268x over previous
//
#include <hip/hip_runtime.h>

#define N_VERT 163842
#define N8_X   1310736              // N_VERT*64/8
#define RPB    256                  // rows per block (8 waves * 32)
#define GRID_MAIN ((N_VERT + RPB - 1) / RPB)   // 641

typedef float  f32x4  __attribute__((ext_vector_type(4)));
typedef short  s16x8  __attribute__((ext_vector_type(8)));

__device__ __forceinline__ unsigned short f2bf(float f) {
  union { float f; unsigned int u; } c; c.f = f;
  unsigned int u = c.u;
  u += 0x7FFFu + ((u >> 16) & 1u);   // RNE truncate to bf16
  return (unsigned short)(u >> 16);
}

__device__ __forceinline__ s16x8 cvt8(const f32x4 a, const f32x4 b) {
  s16x8 h;
  h[0] = (short)f2bf(a[0]); h[1] = (short)f2bf(a[1]);
  h[2] = (short)f2bf(a[2]); h[3] = (short)f2bf(a[3]);
  h[4] = (short)f2bf(b[0]); h[5] = (short)f2bf(b[1]);
  h[6] = (short)f2bf(b[2]); h[7] = (short)f2bf(b[3]);
  return h;
}

// Standalone dtype sniffer (fallback path only).
__global__ void detect64(const unsigned int* __restrict__ hexw, int* __restrict__ flag) {
  __shared__ int any;
  if (threadIdx.x == 0) any = 0;
  __syncthreads();
  if (hexw[2 * threadIdx.x + 1] != 0u) any = 1;
  __syncthreads();
  if (threadIdx.x == 0) *flag = (any == 0) ? 1 : 0;   // 1 => int64, 0 => int32
}

// Fused prep: detect (block 0) + W->Wf frag-layout bf16 (blocks 1..112) + x->xbf (all blocks).
// Wf layout: t = ((ks*4 + hi)*64 + col)*8 + e  ->  W[(ks*32 + hi*8 + e)*64 + col]
__global__ __launch_bounds__(256) void prep(
    const float* __restrict__ x, const unsigned int* __restrict__ hexw,
    const float* __restrict__ W,
    unsigned short* __restrict__ Wf, unsigned short* __restrict__ xbf,
    int* __restrict__ flag)
{
  const int b = blockIdx.x, tid = threadIdx.x;

  if (b == 0) {
    __shared__ int any;
    if (tid == 0) any = 0;
    __syncthreads();
    if (hexw[2 * tid + 1] != 0u) any = 1;
    __syncthreads();
    if (tid == 0) *flag = (any == 0) ? 1 : 0;
  }
  if (b >= 1 && b <= 112) {                  // 112*256 = 28672 = 448*64 exactly
    const int t   = (b - 1) * 256 + tid;
    const int e   = t & 7;
    const int col = (t >> 3) & 63;
    const int hi  = (t >> 9) & 3;
    const int ks  = t >> 11;
    Wf[t] = f2bf(W[(ks * 32 + hi * 8 + e) * 64 + col]);
  }
  // cvt_x, grid-strided over 8-float groups
  const int stride = gridDim.x * 256;
  for (int i = b * 256 + tid; i < N8_X; i += stride) {
    const f32x4* s = (const f32x4*)(x + (size_t)i * 8);
    *(s16x8*)(xbf + (size_t)i * 8) = cvt8(s[0], s[1]);
  }
}

// Barrier-free main kernel. BF=1: gather bf16 xbf rows (128 B), W from Wf (pre-fragged).
//                           BF=0: gather f32 x rows (256 B), W fragged in-kernel from f32.
template <int BF>
__global__ __launch_bounds__(512, 4) void hexconv3(
    const void* __restrict__ xsrc,
    const unsigned int* __restrict__ hexw,
    const void* __restrict__ wsrc,
    const float* __restrict__ bias,
    float* __restrict__ out,
    const int* __restrict__ flag)
{
  __shared__ unsigned short Wl[28672];        // 57344 B, frag layout [ks][hi][col][e]
  __shared__ unsigned int   offb[RPB * 7];    // 7168 B, gathered-row byte offsets

  const int tid = threadIdx.x;
  const int wv  = tid >> 6;                   // wave 0..7, owns rows [32wv, 32wv+32)
  const int ln  = tid & 63;
  const int lo  = ln & 15;
  const int hi  = ln >> 4;
  const int vbase = blockIdx.x * RPB;
  const int is64  = flag ? *flag : 1;

  // ---- stage W into LDS
  if (BF) {
    const s16x8* wsv = (const s16x8*)wsrc;
#pragma unroll
    for (int it = 0; it < 7; ++it)
      ((s16x8*)Wl)[it * 512 + tid] = wsv[it * 512 + tid];
  } else {
    const float* W = (const float*)wsrc;
    for (int it = 0; it < 56; ++it) {
      const int t   = it * 512 + tid;
      const int e   = t & 7;
      const int col = (t >> 3) & 63;
      const int hif = (t >> 9) & 3;
      const int ks  = t >> 11;
      Wl[t] = f2bf(W[(ks * 32 + hif * 8 + e) * 64 + col]);
    }
  }

  // ---- stage 1792 gather byte-offsets into LDS
#pragma unroll
  for (int it = 0; it < 4; ++it) {
    const int g = it * 512 + tid;
    if (g < RPB * 7) {
      unsigned int ib = 0;
      const int v = g / 7;
      if (vbase + v < N_VERT) {
        const unsigned int r = (unsigned int)vbase * 7 + g;
        ib = hexw[r << is64] << (BF ? 7 : 8);
      }
      offb[g] = ib;
    }
  }
  __syncthreads();   // the ONLY barrier

  // ---- per-lane: my two rows' offsets for all 7 ring slots
  const int r0 = wv * 32 + lo, r1 = r0 + 16;
  unsigned int off0[7], off1[7];
#pragma unroll
  for (int j = 0; j < 7; ++j) { off0[j] = offb[r0 * 7 + j]; off1[j] = offb[r1 * 7 + j]; }

  const char* xbase = (const char*)xsrc;
  const char* Wb    = (const char*)Wl + (hi * 64 + lo) * 16;   // + imm (2j+kss)*4096 + nt*256

  f32x4 acc0[4], acc1[4];
#pragma unroll
  for (int nt = 0; nt < 4; ++nt) { acc0[nt] = (f32x4){0,0,0,0}; acc1[nt] = (f32x4){0,0,0,0}; }

  // A-fragment gather: lane reads 16 B at row + kss*64 + hi*16 (bf16) / converts from f32
  s16x8 a[2][2][2];   // [parity][kss][mt]
#define LOAD_A(par, jj)                                                        \
  do {                                                                         \
    const char* p0 = xbase + off0[jj];                                         \
    const char* p1 = xbase + off1[jj];                                         \
    if (BF) {                                                                  \
      a[par][0][0] = *(const s16x8*)(p0 + hi * 16);                            \
      a[par][1][0] = *(const s16x8*)(p0 + 64 + hi * 16);                       \
      a[par][0][1] = *(const s16x8*)(p1 + hi * 16);                            \
      a[par][1][1] = *(const s16x8*)(p1 + 64 + hi * 16);                       \
    } else {                                                                   \
      const f32x4* q0 = (const f32x4*)(p0 + hi * 32);                          \
      const f32x4* q1 = (const f32x4*)(p1 + hi * 32);                          \
      a[par][0][0] = cvt8(q0[0], q0[1]);                                       \
      a[par][1][0] = cvt8(*(const f32x4*)(p0 + 128 + hi * 32),                 \
                          *(const f32x4*)(p0 + 144 + hi * 32));                \
      a[par][0][1] = cvt8(q1[0], q1[1]);                                       \
      a[par][1][1] = cvt8(*(const f32x4*)(p1 + 128 + hi * 32),                 \
                          *(const f32x4*)(p1 + 144 + hi * 32));                \
    }                                                                          \
  } while (0)

  LOAD_A(0, 0);

#pragma unroll
  for (int j = 0; j < 7; ++j) {
    const int cur = j & 1, nxt = cur ^ 1;
    if (j < 6) LOAD_A(nxt, j + 1);          // issue next-j gathers before MFMA phase
#pragma unroll
    for (int kss = 0; kss < 2; ++kss) {
#pragma unroll
      for (int nt = 0; nt < 4; ++nt) {
        const s16x8 bf = *(const s16x8*)(Wb + (2 * j + kss) * 4096 + nt * 256);
        acc0[nt] = __builtin_amdgcn_mfma_f32_16x16x32_bf16(a[cur][kss][0], bf, acc0[nt], 0, 0, 0);
        acc1[nt] = __builtin_amdgcn_mfma_f32_16x16x32_bf16(a[cur][kss][1], bf, acc1[nt], 0, 0, 0);
      }
    }
  }
#undef LOAD_A

  // ---- epilogue: C layout col=lo, row=hi*4+i (verified)
  float bval[4];
#pragma unroll
  for (int nt = 0; nt < 4; ++nt) bval[nt] = bias[nt * 16 + lo];

  const int rbase = vbase + wv * 32;
#pragma unroll
  for (int i = 0; i < 4; ++i) {
    const int row0 = rbase + hi * 4 + i;
    if (row0 < N_VERT) {
      float* orow = out + (size_t)row0 * 64;
#pragma unroll
      for (int nt = 0; nt < 4; ++nt) orow[nt * 16 + lo] = acc0[nt][i] + bval[nt];
    }
    const int row1 = rbase + 16 + hi * 4 + i;
    if (row1 < N_VERT) {
      float* orow = out + (size_t)row1 * 64;
#pragma unroll
      for (int nt = 0; nt < 4; ++nt) orow[nt * 16 + lo] = acc1[nt][i] + bval[nt];
    }
  }
}

extern "C" void kernel_launch(void* const* d_in, const int* in_sizes, int n_in,
                              void* d_out, int out_size, void* d_ws, size_t ws_size,
                              hipStream_t stream) {
  const float*        x    = (const float*)d_in[0];
  const unsigned int* hexw = (const unsigned int*)d_in[1];
  const float*        W    = (const float*)d_in[2];
  const float*        b    = (const float*)d_in[3];
  float*              out  = (float*)d_out;

  const size_t WS_NEED = 65536 + (size_t)N_VERT * 64 * 2;

  if (ws_size >= WS_NEED) {
    int*            flag = (int*)d_ws;
    unsigned short* Wf   = (unsigned short*)((char*)d_ws + 4096);
    unsigned short* xbf  = (unsigned short*)((char*)d_ws + 65536);
    prep<<<2048, 256, 0, stream>>>(x, hexw, W, Wf, xbf, flag);
    hexconv3<1><<<GRID_MAIN, 512, 0, stream>>>(xbf, hexw, Wf, b, out, flag);
  } else {
    int* flag = (ws_size >= 4) ? (int*)d_ws : nullptr;
    if (flag) detect64<<<1, 256, 0, stream>>>(hexw, flag);
    hexconv3<0><<<GRID_MAIN, 512, 0, stream>>>(x, hexw, W, b, out, flag);
  }
}